// Round 6
// baseline (158.840 us; speedup 1.0000x reference)
//
#include <hip/hip_runtime.h>
#include <math.h>

// CTC batch cost (keras.backend.ctc_batch_cost, full lengths).
// B=512, T=512, C=96 (blank=95), L=64, S=2L+1=129.
//
// One 64-lane wave per batch item, wave-synchronous (no barriers).
// Linear-domain forward recurrence; exact power-of-2 rescale every ~8 steps
// (wave max via DPP, exponent via bit ops, scale applied lagged).
//
// Round 6: LDS removed from the READ path entirely.
//  - R5 post-mortem: precise reg-staged LDS writes were neutral vs R4 ->
//    the stall is not the staging waits. Remaining suspects: LDS label
//    gather bank conflicts (~4-6 way on a solo wave), ocml frexpf/ldexpf.
//  - Now: per-step p-values gathered DIRECTLY from global (blank uniform +
//    label per-lane scatter), hitting L2 because coalesced full-row warmer
//    loads (G/H float4 sets, 2 chunks ahead) prefetch every line. Warmer
//    regs kept alive by write-only ds_write_b128 sinks (never read).
//  - Gathers issued 16 steps (~400+ cyc) ahead into named double-buffered
//    scalars (P/Q sets), consume-then-reload interleave; vmcnt <= ~46.
//  - Renorm: DPP wave-max + bit-twiddled exponent (no ocml in the loop).
//  - Step math = exact R1 association (absmax was 16 = 1 bf16 ulp there).

constexpr int Bv = 512;
constexpr int Tv = 512;
constexpr int Cv = 96;
constexpr int Lv = 64;
constexpr int BLANK = Cv - 1;        // 95
constexpr float EPSf = 1e-7f;

constexpr int ROWS = 32;             // rows per warm chunk
constexpr int NCH  = Tv / ROWS;      // 16
constexpr int CF   = ROWS * Cv;      // 3072 floats = 12 KB

__device__ __forceinline__ float dpp_shr1(float x) {   // lane i <- i-1; lane0 <- 0
    return __int_as_float(
        __builtin_amdgcn_update_dpp(0, __float_as_int(x), 0x138, 0xf, 0xf, true));
}
template <int C>
__device__ __forceinline__ float dppmax(float m) {
    return fmaxf(m, __int_as_float(
        __builtin_amdgcn_update_dpp(0, __float_as_int(m), C, 0xf, 0xf, true)));
}

__global__ void __launch_bounds__(64) ctc_fwd(const int* __restrict__ y_true,
                                              const float* __restrict__ y_pred,
                                              float* __restrict__ out) {
    __shared__ float sink_lds[CF];                     // 12 KB, write-only sink

    const int b = blockIdx.x;
    const int l = threadIdx.x;                         // lane 0..63
    const float* __restrict__ yp = y_pred + (size_t)b * (Tv * Cv);

    const int lab   = y_true[b * Lv + l];              // label l (< 95)
    const int labm1 = __shfl_up(lab, 1);
    const bool skip = (l > 0) && (lab != labm1);

    const float* __restrict__ gB = yp + BLANK;         // + t*96: blank column
    const float* __restrict__ gL = yp + lab;           // + t*96: label column

    // ---- coalesced full-row warmers (keep L2 hot ~2 chunks ahead) ----
    float4 G0,G1,G2,G3,G4,G5,G6,G7,G8,G9,G10,G11;
    float4 H0,H1,H2,H3,H4,H5,H6,H7,H8,H9,H10,H11;
#define GLOAD(S, g) do { const float* gp_ = (g) + l * 4;                     \
    S##0 = *(const float4*)(gp_ +    0); S##1 = *(const float4*)(gp_ +  256);\
    S##2 = *(const float4*)(gp_ +  512); S##3 = *(const float4*)(gp_ +  768);\
    S##4 = *(const float4*)(gp_ + 1024); S##5 = *(const float4*)(gp_ + 1280);\
    S##6 = *(const float4*)(gp_ + 1536); S##7 = *(const float4*)(gp_ + 1792);\
    S##8 = *(const float4*)(gp_ + 2048); S##9 = *(const float4*)(gp_ + 2304);\
    S##10= *(const float4*)(gp_ + 2560); S##11= *(const float4*)(gp_ + 2816);\
    } while (0)
#define SINK(S) do { float4* sp_ = (float4*)sink_lds + l;                    \
    sp_[0]   = S##0; sp_[64]  = S##1; sp_[128] = S##2; sp_[192] = S##3;      \
    sp_[256] = S##4; sp_[320] = S##5; sp_[384] = S##6; sp_[448] = S##7;      \
    sp_[512] = S##8; sp_[576] = S##9; sp_[640] = S##10; sp_[704] = S##11;    \
    } while (0)

    GLOAD(G, yp);                                      // chunk 0
    GLOAD(H, yp + CF);                                 // chunk 1

    // ---- gather pipeline: groups of 8 rows, double-buffered P/Q sets ----
    float PB0,PB1,PB2,PB3,PB4,PB5,PB6,PB7, PL0,PL1,PL2,PL3,PL4,PL5,PL6,PL7;
    float QB0,QB1,QB2,QB3,QB4,QB5,QB6,QB7, QL0,QL1,QL2,QL3,QL4,QL5,QL6,QL7;
#define LOADG(P, g) do {                                                     \
    const float* pB_ = gB + (size_t)(8 * (g)) * Cv;                          \
    const float* pL_ = gL + (size_t)(8 * (g)) * Cv;                          \
    P##B0 = pB_[0*Cv]; P##L0 = pL_[0*Cv]; P##B1 = pB_[1*Cv]; P##L1 = pL_[1*Cv];\
    P##B2 = pB_[2*Cv]; P##L2 = pL_[2*Cv]; P##B3 = pB_[3*Cv]; P##L3 = pL_[3*Cv];\
    P##B4 = pB_[4*Cv]; P##L4 = pL_[4*Cv]; P##B5 = pB_[5*Cv]; P##L5 = pL_[5*Cv];\
    P##B6 = pB_[6*Cv]; P##L6 = pL_[6*Cv]; P##B7 = pB_[7*Cv]; P##L7 = pL_[7*Cv];\
    } while (0)

    LOADG(P, 0);                                       // rows 0..7
    LOADG(Q, 1);                                       // rows 8..15

    float a0, a1, a2;                                  // states 2l, 2l+1, 128
    int   e_acc = 0;
    float sc_p = 1.0f; int e_p = 0;                    // lagged renorm state

    auto step = [&](float PB, float PL) {
        float pb  = PB + EPSf;
        float pl  = PL + EPSf;
        float a1p = dpp_shr1(a1);                      // alpha[2l-1]; lane0 -> 0
        float na0 = (a0 + a1p) * pb;                   // state 2l
        float s1  = a0 + a1 + (skip ? a1p : 0.0f);     // state 2l+1 (R1 assoc)
        float na1 = s1 * pl;
        float na2 = (a2 + a1) * pb;                    // state 128 (lane 63)
        a0 = na0; a1 = na1; a2 = na2;
    };
    auto rn_apply = [&]() {                            // apply lagged pow2 scale
        a0 *= sc_p; a1 *= sc_p; a2 *= sc_p; e_acc += e_p;
    };
    auto rn_compute = [&]() {                          // wave max -> exact 2^-e
        float m = fmaxf(fmaxf(a0, a1), a2);
        m = dppmax<0x111>(m); m = dppmax<0x112>(m); m = dppmax<0x114>(m);
        m = dppmax<0x118>(m); m = dppmax<0x142>(m); m = dppmax<0x143>(m);
        float mw = __int_as_float(__builtin_amdgcn_readlane(__float_as_int(m), 63));
        unsigned ef = __float_as_uint(mw) >> 23;       // biased exp (mw normal >0)
        e_p  = (int)ef - 126;                          // mw * 2^-e in [0.5,1)
        sc_p = __uint_as_float((253u - ef) << 23);     // exact 2^-e
    };

    // consume slot i of set P (group g), then reload slot for group g+2
#define STEP_PF(P, i) do { step(P##B##i, P##L##i);                           \
    P##B##i = pB2[(i) * Cv]; P##L##i = pL2[(i) * Cv]; } while (0)
#define GROUP(P, g) do {                                                     \
    int r20_ = 8 * ((g) + 2); if (r20_ > Tv - 8) r20_ = Tv - 8;              \
    const float* pB2 = gB + (size_t)r20_ * Cv;                               \
    const float* pL2 = gL + (size_t)r20_ * Cv;                               \
    STEP_PF(P,0); STEP_PF(P,1); STEP_PF(P,2); STEP_PF(P,3); rn_apply();      \
    STEP_PF(P,4); STEP_PF(P,5); STEP_PF(P,6); STEP_PF(P,7); rn_compute();    \
    } while (0)

    // ---- group 0 (t=0 init + steps t=1..7), prefetch group 2 ----
    {
        const bool lane0 = (l == 0);
        a0 = lane0 ? (PB0 + EPSf) : 0.0f;
        a1 = lane0 ? (PL0 + EPSf) : 0.0f;
        a2 = 0.0f;
        const float* pB2 = gB + (size_t)16 * Cv;
        const float* pL2 = gL + (size_t)16 * Cv;
        PB0 = pB2[0]; PL0 = pL2[0];                    // refill consumed slot 0
        STEP_PF(P,1); STEP_PF(P,2); STEP_PF(P,3); rn_apply();
        STEP_PF(P,4); STEP_PF(P,5); STEP_PF(P,6); STEP_PF(P,7); rn_compute();
    }

    // ---- chunk 0 remainder: groups 1(Q), 2(P), 3(Q); warm chunk 2 ----
    SINK(G); GLOAD(G, yp + 2 * CF);
    GROUP(Q, 1); GROUP(P, 2); GROUP(Q, 3);

    // ---- chunks 1..15: groups 4c..4c+3 = P,Q,P,Q; warm chunk c+2 ----
    for (int c = 1; c < NCH; ++c) {
        if (c <= NCH - 3) {
            if (c & 1) { SINK(H); GLOAD(H, yp + (size_t)(c + 2) * CF); }
            else       { SINK(G); GLOAD(G, yp + (size_t)(c + 2) * CF); }
        }
        int g = 4 * c;
        GROUP(P, g); GROUP(Q, g + 1); GROUP(P, g + 2); GROUP(Q, g + 3);
    }

    // ---- loss = -logaddexp(alpha[127], alpha[128]) ----
    if (l == 63) {
        float sum = a1 + a2;                           // states 127 + 128
        out[b] = -(logf(sum) + (float)e_acc * 0.69314718055994530942f);
    }
#undef GLOAD
#undef SINK
#undef LOADG
#undef STEP_PF
#undef GROUP
}

extern "C" void kernel_launch(void* const* d_in, const int* in_sizes, int n_in,
                              void* d_out, int out_size, void* d_ws, size_t ws_size,
                              hipStream_t stream) {
    const int*   y_true = (const int*)d_in[0];   // [512, 64] int32
    const float* y_pred = (const float*)d_in[1]; // [512, 512, 96] fp32
    float*       out    = (float*)d_out;         // [512, 1] fp32
    (void)in_sizes; (void)n_in; (void)out_size; (void)d_ws; (void)ws_size;
    ctc_fwd<<<Bv, 64, 0, stream>>>(y_true, y_pred, out);
}

// Round 7
// 153.948 us; speedup vs baseline: 1.0318x; 1.0318x over previous
//
#include <hip/hip_runtime.h>
#include <math.h>

// CTC batch cost (keras.backend.ctc_batch_cost, full lengths).
// B=512, T=512, C=96 (blank=95), L=64, S=2L+1=129.
//
// Round 7: producer-consumer wave specialization (4 waves / block).
//  - R3-R6 post-mortem: three memory-path rewrites in the single-wave
//    skeleton all land 40-56 us (~190 cyc/step vs ~12 paper) -> exposed
//    latency with nothing co-resident to overlap it (2 waves/CU).
//  - Wave 0 (consumer): runs the recurrence; reads ONLY LDS; zero global
//    loads, zero vmcnt waits. 2 ds_read/step prefetched >=8 steps ahead.
//  - Waves 1-3 (producers): stream y_pred 32-row chunks into a 4-slot LDS
//    ring (rows padded to 100 floats) via coalesced float4 loads ->
//    ds_write_b128. Flow control: monotonic chunk-index flags in LDS,
//    volatile polls + s_sleep, lgkmcnt(0) release before flag store.
//  - 2 blocks/CU -> 8 waves/CU; producer HBM latency overlaps consumer.
//  - Numerics identical to R6: linear-domain recurrence, DPP wave-max,
//    bit-twiddled exact 2^-e scale, lag-applied; renorm every 8 steps.

constexpr int Bv = 512;
constexpr int Tv = 512;
constexpr int Cv = 96;
constexpr int Lv = 64;
constexpr int BLANK = Cv - 1;        // 95
constexpr float EPSf = 1e-7f;

constexpr int ROWS = 32;             // rows per chunk
constexpr int NCH  = Tv / ROWS;      // 16 chunks
constexpr int CF   = ROWS * Cv;      // 3072 floats per chunk (global)
constexpr int RS   = 100;            // padded LDS row stride (floats)
constexpr int SLOTF = ROWS * RS;     // 3200 floats per ring slot
constexpr int NSLOT = 4;             // ring slots (4 x 12.8 KB = 51.2 KB)

__device__ __forceinline__ float dpp_shr1(float x) {   // lane i <- i-1; lane0 <- 0
    return __int_as_float(
        __builtin_amdgcn_update_dpp(0, __float_as_int(x), 0x138, 0xf, 0xf, true));
}
template <int C>
__device__ __forceinline__ float dppmax(float m) {
    return fmaxf(m, __int_as_float(
        __builtin_amdgcn_update_dpp(0, __float_as_int(m), C, 0xf, 0xf, true)));
}

__global__ void __launch_bounds__(256, 2) ctc_fwd(const int* __restrict__ y_true,
                                                  const float* __restrict__ y_pred,
                                                  float* __restrict__ out) {
    __shared__ float ring[NSLOT * SLOTF];              // 51.2 KB
    __shared__ int   flags[8];    // [0..3] = slot chunk-flag (c+1), [4] = cons_done

    const int b = blockIdx.x;
    const int w = threadIdx.x >> 6;                    // wave 0..3
    const int l = threadIdx.x & 63;                    // lane 0..63
    const float* __restrict__ yp = y_pred + (size_t)b * (Tv * Cv);

    if (threadIdx.x < 8) flags[threadIdx.x] = 0;
    __syncthreads();                                   // only barrier in kernel

    if (w != 0) {
        // ================= producers: waves 1..3, chunks c = w-1 (mod 3) ======
#define WA(i) ((((i)*64 + l) / 24) * (RS * 4) + (((i)*64 + l) % 24) * 16)
        const int wa0 = WA(0),  wa1 = WA(1),  wa2 = WA(2),  wa3 = WA(3);
        const int wa4 = WA(4),  wa5 = WA(5),  wa6 = WA(6),  wa7 = WA(7);
        const int wa8 = WA(8),  wa9 = WA(9), wa10 = WA(10), wa11 = WA(11);
#undef WA
        float4 G0,G1,G2,G3,G4,G5,G6,G7,G8,G9,G10,G11;
#define GLOAD(g) do { const float* gp_ = (g) + l * 4;                        \
    G0 = *(const float4*)(gp_ +    0); G1 = *(const float4*)(gp_ +  256);    \
    G2 = *(const float4*)(gp_ +  512); G3 = *(const float4*)(gp_ +  768);    \
    G4 = *(const float4*)(gp_ + 1024); G5 = *(const float4*)(gp_ + 1280);    \
    G6 = *(const float4*)(gp_ + 1536); G7 = *(const float4*)(gp_ + 1792);    \
    G8 = *(const float4*)(gp_ + 2048); G9 = *(const float4*)(gp_ + 2304);    \
    G10= *(const float4*)(gp_ + 2560); G11= *(const float4*)(gp_ + 2816);    \
    } while (0)
#define SWRITE(base) do { char* p_ = (char*)(base);                          \
    *(float4*)(p_ + wa0) = G0;  *(float4*)(p_ + wa1) = G1;                   \
    *(float4*)(p_ + wa2) = G2;  *(float4*)(p_ + wa3) = G3;                   \
    *(float4*)(p_ + wa4) = G4;  *(float4*)(p_ + wa5) = G5;                   \
    *(float4*)(p_ + wa6) = G6;  *(float4*)(p_ + wa7) = G7;                   \
    *(float4*)(p_ + wa8) = G8;  *(float4*)(p_ + wa9) = G9;                   \
    *(float4*)(p_ + wa10)= G10; *(float4*)(p_ + wa11)= G11; } while (0)

        volatile int* cd = &flags[4];
        int c = w - 1;
        GLOAD(yp + (size_t)c * CF);
        while (c < NCH) {
            while (*cd < c - (NSLOT - 1)) __builtin_amdgcn_s_sleep(8);
            SWRITE((char*)ring + (size_t)(c & (NSLOT - 1)) * (SLOTF * 4));
            __builtin_amdgcn_s_waitcnt(0xC07F);        // lgkmcnt(0): release
            __asm__ __volatile__("" ::: "memory");
            if (l == 0) *((volatile int*)&flags[c & (NSLOT - 1)]) = c + 1;
            c += 3;
            if (c < NCH) GLOAD(yp + (size_t)c * CF);
        }
#undef GLOAD
#undef SWRITE
        return;
    }

    // ================= consumer: wave 0 =====================================
    const int lab   = y_true[b * Lv + l];              // label l (< 95)
    const int labm1 = __shfl_up(lab, 1);
    const bool skip = (l > 0) && (lab != labm1);
    const bool lane0 = (l == 0);

    float a0, a1, a2;                                  // states 2l, 2l+1, 128
    int   e_acc = 0;
    float sc_p = 1.0f; int e_p = 0;                    // lagged renorm state

    auto step = [&](float PB, float PL) {
        float pb  = PB + EPSf;
        float pl  = PL + EPSf;
        float a1p = dpp_shr1(a1);                      // alpha[2l-1]; lane0 -> 0
        float na0 = (a0 + a1p) * pb;                   // state 2l
        float s1  = a0 + a1 + (skip ? a1p : 0.0f);     // state 2l+1
        float na1 = s1 * pl;
        float na2 = (a2 + a1) * pb;                    // state 128 (lane 63)
        a0 = na0; a1 = na1; a2 = na2;
    };
    auto rn_apply = [&]() { a0 *= sc_p; a1 *= sc_p; a2 *= sc_p; e_acc += e_p; };
    auto rn_compute = [&]() {
        float m = fmaxf(fmaxf(a0, a1), a2);
        m = dppmax<0x111>(m); m = dppmax<0x112>(m); m = dppmax<0x114>(m);
        m = dppmax<0x118>(m); m = dppmax<0x142>(m); m = dppmax<0x143>(m);
        float mw = __int_as_float(__builtin_amdgcn_readlane(__float_as_int(m), 63));
        unsigned ef = __float_as_uint(mw) >> 23;       // biased exp (mw normal >0)
        e_p  = (int)ef - 126;
        sc_p = __uint_as_float((253u - ef) << 23);     // exact 2^-e
    };

    float PB0,PB1,PB2,PB3,PB4,PB5,PB6,PB7, PL0,PL1,PL2,PL3,PL4,PL5,PL6,PL7;
    float QB0,QB1,QB2,QB3,QB4,QB5,QB6,QB7, QL0,QL1,QL2,QL3,QL4,QL5,QL6,QL7;
#define LOAD8(P, sb, r0) do {                                                \
    const float* pB_ = (sb) + (r0) * RS + BLANK;                             \
    const float* pL_ = (sb) + (r0) * RS + lab;                               \
    P##B0 = pB_[0*RS]; P##L0 = pL_[0*RS]; P##B1 = pB_[1*RS]; P##L1 = pL_[1*RS];\
    P##B2 = pB_[2*RS]; P##L2 = pL_[2*RS]; P##B3 = pB_[3*RS]; P##L3 = pL_[3*RS];\
    P##B4 = pB_[4*RS]; P##L4 = pL_[4*RS]; P##B5 = pB_[5*RS]; P##L5 = pL_[5*RS];\
    P##B6 = pB_[6*RS]; P##L6 = pL_[6*RS]; P##B7 = pB_[7*RS]; P##L7 = pL_[7*RS];\
    } while (0)
#define STEP_RL(P, i) do { step(P##B##i, P##L##i);                           \
    P##B##i = rb_[(i) * RS]; P##L##i = rl_[(i) * RS]; } while (0)
#define GROUP_RL(P, sb, r16) do {                                            \
    const float* rb_ = (sb) + (r16) * RS + BLANK;                            \
    const float* rl_ = (sb) + (r16) * RS + lab;                              \
    STEP_RL(P,0); STEP_RL(P,1); STEP_RL(P,2); STEP_RL(P,3); rn_apply();      \
    STEP_RL(P,4); STEP_RL(P,5); STEP_RL(P,6); STEP_RL(P,7); rn_compute();    \
    } while (0)
#define GROUP_N(P) do {                                                      \
    step(P##B0,P##L0); step(P##B1,P##L1); step(P##B2,P##L2); step(P##B3,P##L3);\
    rn_apply();                                                              \
    step(P##B4,P##L4); step(P##B5,P##L5); step(P##B6,P##L6); step(P##B7,P##L7);\
    rn_compute(); } while (0)

    volatile int* vf = flags;

    // ---- chunk 0: t=0 init + t=1..31 ----
    while (vf[0] != 1) __builtin_amdgcn_s_sleep(8);
    __asm__ __volatile__("" ::: "memory");
    {
        const float* sb = ring;
        LOAD8(P, sb, 0); LOAD8(Q, sb, 8);
        a0 = lane0 ? (PB0 + EPSf) : 0.0f;
        a1 = lane0 ? (PL0 + EPSf) : 0.0f;
        a2 = 0.0f;
        {   // group 0: init consumed slot 0; steps t=1..7, reload rows 16..23
            const float* rb_ = sb + 16 * RS + BLANK;
            const float* rl_ = sb + 16 * RS + lab;
            PB0 = rb_[0]; PL0 = rl_[0];
            STEP_RL(P,1); STEP_RL(P,2); STEP_RL(P,3); rn_apply();
            STEP_RL(P,4); STEP_RL(P,5); STEP_RL(P,6); STEP_RL(P,7); rn_compute();
        }
        GROUP_RL(Q, sb, 24);                           // t=8..15, reload 24..31
        GROUP_N(P);                                    // t=16..23
        GROUP_N(Q);                                    // t=24..31
    }
    __asm__ __volatile__("" ::: "memory");
    if (l == 0) *((volatile int*)&flags[4]) = 1;

    // ---- chunks 1..15 ----
    for (int c = 1; c < NCH; ++c) {
        while (vf[c & (NSLOT - 1)] != c + 1) __builtin_amdgcn_s_sleep(8);
        __asm__ __volatile__("" ::: "memory");
        const float* sb = ring + (size_t)(c & (NSLOT - 1)) * SLOTF;
        LOAD8(P, sb, 0); LOAD8(Q, sb, 8);
        GROUP_RL(P, sb, 16);                           // rows 0-7, reload 16-23
        GROUP_RL(Q, sb, 24);                           // rows 8-15, reload 24-31
        GROUP_N(P);                                    // rows 16-23
        GROUP_N(Q);                                    // rows 24-31
        __asm__ __volatile__("" ::: "memory");
        if (l == 0) *((volatile int*)&flags[4]) = c + 1;
    }

    // ---- loss = -logaddexp(alpha[127], alpha[128]) ----
    if (l == 63) {
        float sum = a1 + a2;                           // states 127 + 128
        out[b] = -(logf(sum) + (float)e_acc * 0.69314718055994530942f);
    }
#undef LOAD8
#undef STEP_RL
#undef GROUP_RL
#undef GROUP_N
}

extern "C" void kernel_launch(void* const* d_in, const int* in_sizes, int n_in,
                              void* d_out, int out_size, void* d_ws, size_t ws_size,
                              hipStream_t stream) {
    const int*   y_true = (const int*)d_in[0];   // [512, 64] int32
    const float* y_pred = (const float*)d_in[1]; // [512, 512, 96] fp32
    float*       out    = (float*)d_out;         // [512, 1] fp32
    (void)in_sizes; (void)n_in; (void)out_size; (void)d_ws; (void)ws_size;
    ctc_fwd<<<Bv, 256, 0, stream>>>(y_true, y_pred, out);
}

// Round 8
// 153.422 us; speedup vs baseline: 1.0353x; 1.0034x over previous
//
#include <hip/hip_runtime.h>
#include <math.h>

// CTC batch cost (keras.backend.ctc_batch_cost, full lengths).
// B=512, T=512, C=96 (blank=95), L=64, S=2L+1=129.
//
// Round 8: lean the serial program (R7 skeleton kept).
//  - R5/R6/R7 post-mortem: per-step cost ~190-215 cyc is invariant to the
//    memory path -> the consumer's in-order instruction stream is the wall.
//    Levers: fewer instructions/step + fewer stall events.
//  - Lean step = 8 VALU: EPS pre-added by producers; skip as float mask m,
//    u = fmaf(a1p, m, a0+a1) == cndmask+add bit-exactly (m in {0,1}).
//  - s_sleep(1)/(2) polls (were 8 = ~512 cyc quantization per wait).
//  - Producers: double-set (G/H) load pipeline -> ds_write's vmcnt wait
//    covers only the 2-iteration-old set (per-register vmcnt, precise);
//    first GLOADs hoisted before __syncthreads.
//  - Renorm cadence stays 8 (cadence 16 underflows: decay ~2^-6.6/step
//    means a 24-step worst window hits 2^-159 < denorm min).

constexpr int Bv = 512;
constexpr int Tv = 512;
constexpr int Cv = 96;
constexpr int Lv = 64;
constexpr int BLANK = Cv - 1;        // 95
constexpr float EPSf = 1e-7f;

constexpr int ROWS = 32;             // rows per chunk
constexpr int NCH  = Tv / ROWS;      // 16 chunks
constexpr int CF   = ROWS * Cv;      // 3072 floats per chunk (global)
constexpr int RS   = 100;            // padded LDS row stride (floats)
constexpr int SLOTF = ROWS * RS;     // 3200 floats per ring slot
constexpr int NSLOT = 4;             // 4 x 12.8 KB = 51.2 KB

__device__ __forceinline__ float dpp_shr1(float x) {   // lane i <- i-1; lane0 <- 0
    return __int_as_float(
        __builtin_amdgcn_update_dpp(0, __float_as_int(x), 0x138, 0xf, 0xf, true));
}
template <int C>
__device__ __forceinline__ float dppmax(float m) {
    return fmaxf(m, __int_as_float(
        __builtin_amdgcn_update_dpp(0, __float_as_int(m), C, 0xf, 0xf, true)));
}
__device__ __forceinline__ float4 addeps(float4 v) {
    v.x += EPSf; v.y += EPSf; v.z += EPSf; v.w += EPSf; return v;
}

__global__ void __launch_bounds__(256, 2) ctc_fwd(const int* __restrict__ y_true,
                                                  const float* __restrict__ y_pred,
                                                  float* __restrict__ out) {
    __shared__ float ring[NSLOT * SLOTF];              // 51.2 KB
    __shared__ int   flags[8];    // [0..3]=slot chunk-flag (c+1), [4]=cons_done

    const int b = blockIdx.x;
    const int w = threadIdx.x >> 6;                    // wave 0..3
    const int l = threadIdx.x & 63;                    // lane 0..63
    const float* __restrict__ yp = y_pred + (size_t)b * (Tv * Cv);

    if (w != 0) {
        // ================= producers: waves 1..3, chunks c = w-1 (mod 3) ====
#define WA(i) ((((i)*64 + l) / 24) * (RS * 4) + (((i)*64 + l) % 24) * 16)
        const int wa0 = WA(0),  wa1 = WA(1),  wa2 = WA(2),  wa3 = WA(3);
        const int wa4 = WA(4),  wa5 = WA(5),  wa6 = WA(6),  wa7 = WA(7);
        const int wa8 = WA(8),  wa9 = WA(9), wa10 = WA(10), wa11 = WA(11);
#undef WA
        float4 G0,G1,G2,G3,G4,G5,G6,G7,G8,G9,G10,G11;
        float4 H0,H1,H2,H3,H4,H5,H6,H7,H8,H9,H10,H11;
#define GLOAD(S, g) do { const float* gp_ = (g) + l * 4;                     \
    S##0 = *(const float4*)(gp_ +    0); S##1 = *(const float4*)(gp_ +  256);\
    S##2 = *(const float4*)(gp_ +  512); S##3 = *(const float4*)(gp_ +  768);\
    S##4 = *(const float4*)(gp_ + 1024); S##5 = *(const float4*)(gp_ + 1280);\
    S##6 = *(const float4*)(gp_ + 1536); S##7 = *(const float4*)(gp_ + 1792);\
    S##8 = *(const float4*)(gp_ + 2048); S##9 = *(const float4*)(gp_ + 2304);\
    S##10= *(const float4*)(gp_ + 2560); S##11= *(const float4*)(gp_ + 2816);\
    } while (0)
#define EPSADD(S) do {                                                       \
    S##0=addeps(S##0); S##1=addeps(S##1); S##2=addeps(S##2);                 \
    S##3=addeps(S##3); S##4=addeps(S##4); S##5=addeps(S##5);                 \
    S##6=addeps(S##6); S##7=addeps(S##7); S##8=addeps(S##8);                 \
    S##9=addeps(S##9); S##10=addeps(S##10); S##11=addeps(S##11); } while (0)
#define SWRITE(S, base) do { char* p_ = (char*)(base);                       \
    *(float4*)(p_ + wa0) = S##0;  *(float4*)(p_ + wa1) = S##1;               \
    *(float4*)(p_ + wa2) = S##2;  *(float4*)(p_ + wa3) = S##3;               \
    *(float4*)(p_ + wa4) = S##4;  *(float4*)(p_ + wa5) = S##5;               \
    *(float4*)(p_ + wa6) = S##6;  *(float4*)(p_ + wa7) = S##7;               \
    *(float4*)(p_ + wa8) = S##8;  *(float4*)(p_ + wa9) = S##9;               \
    *(float4*)(p_ + wa10)= S##10; *(float4*)(p_ + wa11)= S##11; } while (0)

        int c = w - 1;
        GLOAD(G, yp + (size_t)c * CF);                 // before the barrier:
        if (c + 3 < NCH) GLOAD(H, yp + (size_t)(c + 3) * CF);  // warm start
        if (l < 8) flags[l] = 0;                       // wave1 lanes also init?
        __syncthreads();                               // flags visible

        volatile int* cd = &flags[4];
        bool useG = true;
        while (c < NCH) {
            while (*cd < c - (NSLOT - 1)) __builtin_amdgcn_s_sleep(2);
            char* base = (char*)ring + (size_t)(c & (NSLOT - 1)) * (SLOTF * 4);
            if (useG) { EPSADD(G); SWRITE(G, base); }
            else      { EPSADD(H); SWRITE(H, base); }
            __builtin_amdgcn_s_waitcnt(0xC07F);        // lgkmcnt(0): release
            __asm__ __volatile__("" ::: "memory");
            if (l == 0) *((volatile int*)&flags[c & (NSLOT - 1)]) = c + 1;
            int cn = c + 6;
            if (cn < NCH) {
                if (useG) GLOAD(G, yp + (size_t)cn * CF);
                else      GLOAD(H, yp + (size_t)cn * CF);
            }
            useG = !useG; c += 3;
        }
#undef GLOAD
#undef EPSADD
#undef SWRITE
        return;
    }

    // ================= consumer: wave 0 ====================================
    const int lab   = y_true[b * Lv + l];              // label l (< 95)
    const int labm1 = __shfl_up(lab, 1);
    const float m   = ((l > 0) && (lab != labm1)) ? 1.0f : 0.0f;  // skip mask
    const bool lane0 = (l == 0);
    if (threadIdx.x < 8) flags[threadIdx.x] = 0;       // (w==0 covers 0..7)
    __syncthreads();

    float a0, a1, a2;                                  // states 2l, 2l+1, 128
    int   e_acc = 0;
    float sc_p = 1.0f; int e_p = 0;                    // lagged renorm state

    auto step = [&](float PB, float PL) {              // 8 VALU; EPS pre-added
        float a1p = dpp_shr1(a1);                      // alpha[2l-1]; lane0 -> 0
        float t0  = a0 + a1p;
        float na0 = t0 * PB;                           // state 2l
        float t01 = a0 + a1;
        float u   = fmaf(a1p, m, t01);                 // == t01 + (skip? a1p:0)
        float na1 = u * PL;                            // state 2l+1
        float t2  = a2 + a1;
        float na2 = t2 * PB;                           // state 128 (lane 63)
        a0 = na0; a1 = na1; a2 = na2;
    };
    auto rn_apply = [&]() { a0 *= sc_p; a1 *= sc_p; a2 *= sc_p; e_acc += e_p; };
    auto rn_compute = [&]() {
        float mx = fmaxf(fmaxf(a0, a1), a2);
        mx = dppmax<0x111>(mx); mx = dppmax<0x112>(mx); mx = dppmax<0x114>(mx);
        mx = dppmax<0x118>(mx); mx = dppmax<0x142>(mx); mx = dppmax<0x143>(mx);
        float mw = __int_as_float(__builtin_amdgcn_readlane(__float_as_int(mx), 63));
        unsigned ef = __float_as_uint(mw) >> 23;       // biased exp (mw normal >0)
        e_p  = (int)ef - 126;
        sc_p = __uint_as_float((253u - ef) << 23);     // exact 2^-e
    };

    float PB0,PB1,PB2,PB3,PB4,PB5,PB6,PB7, PL0,PL1,PL2,PL3,PL4,PL5,PL6,PL7;
    float QB0,QB1,QB2,QB3,QB4,QB5,QB6,QB7, QL0,QL1,QL2,QL3,QL4,QL5,QL6,QL7;
#define LOAD8(P, sb, r0) do {                                                \
    const float* pB_ = (sb) + (r0) * RS + BLANK;                             \
    const float* pL_ = (sb) + (r0) * RS + lab;                               \
    P##B0 = pB_[0*RS]; P##L0 = pL_[0*RS]; P##B1 = pB_[1*RS]; P##L1 = pL_[1*RS];\
    P##B2 = pB_[2*RS]; P##L2 = pL_[2*RS]; P##B3 = pB_[3*RS]; P##L3 = pL_[3*RS];\
    P##B4 = pB_[4*RS]; P##L4 = pL_[4*RS]; P##B5 = pB_[5*RS]; P##L5 = pL_[5*RS];\
    P##B6 = pB_[6*RS]; P##L6 = pL_[6*RS]; P##B7 = pB_[7*RS]; P##L7 = pL_[7*RS];\
    } while (0)
#define STEP_RL(P, i) do { step(P##B##i, P##L##i);                           \
    P##B##i = rb_[(i) * RS]; P##L##i = rl_[(i) * RS]; } while (0)
#define GROUP_RL(P, sb, r16) do {                                            \
    const float* rb_ = (sb) + (r16) * RS + BLANK;                            \
    const float* rl_ = (sb) + (r16) * RS + lab;                              \
    STEP_RL(P,0); STEP_RL(P,1); STEP_RL(P,2); STEP_RL(P,3); rn_apply();      \
    STEP_RL(P,4); STEP_RL(P,5); STEP_RL(P,6); STEP_RL(P,7); rn_compute();    \
    } while (0)
#define GROUP_N(P) do {                                                      \
    step(P##B0,P##L0); step(P##B1,P##L1); step(P##B2,P##L2); step(P##B3,P##L3);\
    rn_apply();                                                              \
    step(P##B4,P##L4); step(P##B5,P##L5); step(P##B6,P##L6); step(P##B7,P##L7);\
    rn_compute(); } while (0)

    volatile int* vf = flags;

    // ---- chunk 0: t=0 init + t=1..31 ----
    while (vf[0] != 1) __builtin_amdgcn_s_sleep(1);
    __asm__ __volatile__("" ::: "memory");
    {
        const float* sb = ring;
        LOAD8(P, sb, 0); LOAD8(Q, sb, 8);
        a0 = lane0 ? PB0 : 0.0f;                       // EPS already included
        a1 = lane0 ? PL0 : 0.0f;
        a2 = 0.0f;
        {   // group 0: steps t=1..7, reload rows 16..23
            const float* rb_ = sb + 16 * RS + BLANK;
            const float* rl_ = sb + 16 * RS + lab;
            PB0 = rb_[0]; PL0 = rl_[0];
            STEP_RL(P,1); STEP_RL(P,2); STEP_RL(P,3); rn_apply();
            STEP_RL(P,4); STEP_RL(P,5); STEP_RL(P,6); STEP_RL(P,7); rn_compute();
        }
        GROUP_RL(Q, sb, 24);                           // t=8..15, reload 24..31
        GROUP_N(P);                                    // t=16..23
        GROUP_N(Q);                                    // t=24..31
    }
    __asm__ __volatile__("" ::: "memory");
    if (l == 0) *((volatile int*)&flags[4]) = 1;

    // ---- chunks 1..15 ----
    for (int c = 1; c < NCH; ++c) {
        while (vf[c & (NSLOT - 1)] != c + 1) __builtin_amdgcn_s_sleep(1);
        __asm__ __volatile__("" ::: "memory");
        const float* sb = ring + (size_t)(c & (NSLOT - 1)) * SLOTF;
        LOAD8(P, sb, 0); LOAD8(Q, sb, 8);
        GROUP_RL(P, sb, 16);                           // rows 0-7, reload 16-23
        GROUP_RL(Q, sb, 24);                           // rows 8-15, reload 24-31
        GROUP_N(P);                                    // rows 16-23
        GROUP_N(Q);                                    // rows 24-31
        __asm__ __volatile__("" ::: "memory");
        if (l == 0) *((volatile int*)&flags[4]) = c + 1;
    }

    // ---- loss = -logaddexp(alpha[127], alpha[128]) ----
    if (l == 63) {
        float sum = a1 + a2;                           // states 127 + 128
        out[b] = -(logf(sum) + (float)e_acc * 0.69314718055994530942f);
    }
#undef LOAD8
#undef STEP_RL
#undef GROUP_RL
#undef GROUP_N
}

extern "C" void kernel_launch(void* const* d_in, const int* in_sizes, int n_in,
                              void* d_out, int out_size, void* d_ws, size_t ws_size,
                              hipStream_t stream) {
    const int*   y_true = (const int*)d_in[0];   // [512, 64] int32
    const float* y_pred = (const float*)d_in[1]; // [512, 512, 96] fp32
    float*       out    = (float*)d_out;         // [512, 1] fp32
    (void)in_sizes; (void)n_in; (void)out_size; (void)d_ws; (void)ws_size;
    ctc_fwd<<<Bv, 256, 0, stream>>>(y_true, y_pred, out);
}